// Round 3
// baseline (550.031 us; speedup 1.0000x reference)
//
#include <hip/hip_runtime.h>

// GAQN actor: segmented gumbel-max sampling + reversed row gather.
// N elements, B segments (batch_idx sorted, int32), D=64 candidate dim.

#define N_ELEMS 1048576
#define BSEG    16384
#define DDIM    64

// Gumbel bit-layout variant:
//  0 = JAX partitionable threefry (default since jax 0.4.36): bits = o0 ^ o1, x=(0,i)
//  1 = JAX original: pairs (i, i+N/2) -> o0 for first half, o1 for second half
//  2 = partitionable, take o1 only
//  3 = partitionable, take o0 only
#define GUMBEL_VARIANT 0

__device__ __forceinline__ unsigned rotl32(unsigned x, unsigned r) {
    return (x << r) | (x >> (32u - r));
}

#define TF_ROUND(r) { x0 += x1; x1 = rotl32(x1, (r)); x1 ^= x0; }

// Threefry-2x32, 20 rounds, key = (0, 42)  [jax.random.key(42) -> (0,42)]
__device__ __forceinline__ void tf2x32(unsigned x0, unsigned x1,
                                       unsigned& o0, unsigned& o1) {
    const unsigned k0 = 0u, k1 = 42u;
    const unsigned ks2 = k0 ^ k1 ^ 0x1BD11BDAu;
    x0 += k0; x1 += k1;
    TF_ROUND(13) TF_ROUND(15) TF_ROUND(26) TF_ROUND(6)
    x0 += k1; x1 += ks2 + 1u;
    TF_ROUND(17) TF_ROUND(29) TF_ROUND(16) TF_ROUND(24)
    x0 += ks2; x1 += k0 + 2u;
    TF_ROUND(13) TF_ROUND(15) TF_ROUND(26) TF_ROUND(6)
    x0 += k0; x1 += k1 + 3u;
    TF_ROUND(17) TF_ROUND(29) TF_ROUND(16) TF_ROUND(24)
    x0 += k1; x1 += ks2 + 4u;
    TF_ROUND(13) TF_ROUND(15) TF_ROUND(26) TF_ROUND(6)
    x0 += ks2; x1 += k0 + 5u;
    o0 = x0; o1 = x1;
}

__device__ __forceinline__ unsigned gumbel_bits(unsigned i) {
#if GUMBEL_VARIANT == 1
    unsigned a, b;
    if (i < (N_ELEMS / 2)) { tf2x32(i, i + (N_ELEMS / 2), a, b); return a; }
    else                   { tf2x32(i - (N_ELEMS / 2), i, a, b); return b; }
#else
    unsigned a, b;
    tf2x32(0u, i, a, b);
  #if GUMBEL_VARIANT == 0
    return a ^ b;
  #elif GUMBEL_VARIANT == 2
    return b;
  #else
    return a;
  #endif
#endif
}

// Reproduces jax.random.gumbel(key(42), (N,), float32) element i.
// uniform: f = bitcast((bits>>9)|0x3f800000) - 1.0; u = max(tiny, f*1.0f + tiny)
__device__ __forceinline__ float gumbel_val(unsigned i) {
    unsigned bits = gumbel_bits(i);
    float f = __uint_as_float((bits >> 9) | 0x3f800000u) - 1.0f;
    const float tiny = 1.17549435e-38f;  // FLT_MIN
    float u = fmaxf(tiny, f + tiny);
    return -logf(-logf(u));
}

// Order-preserving float->uint32 encode (monotone over all finite floats)
__device__ __forceinline__ unsigned fenc(float f) {
    unsigned b = __float_as_uint(f);
    return (b & 0x80000000u) ? ~b : (b | 0x80000000u);
}
__device__ __forceinline__ float fdec(unsigned e) {
    unsigned b = (e & 0x80000000u) ? (e ^ 0x80000000u) : ~e;
    return __uint_as_float(b);
}

// Pass 1: per-segment count and value-max via atomics.
__global__ void k_stats(const float* __restrict__ vals,
                        const int* __restrict__ idx,
                        unsigned* __restrict__ cnt,
                        unsigned* __restrict__ vmax) {
    int i = blockIdx.x * blockDim.x + threadIdx.x;
    if (i >= N_ELEMS) return;
    int b = idx[i];
    atomicAdd(&cnt[b], 1u);
    atomicMax(&vmax[b], fenc(vals[i]));
}

// Pass 2: score = log(probs) + gumbel; segmented argmax with max-id tiebreak
// via atomicMax on (enc(score)<<32 | id).
__global__ void k_score(const float* __restrict__ vals,
                        const int* __restrict__ idx,
                        const unsigned* __restrict__ cnt,
                        const unsigned* __restrict__ vmax,
                        unsigned long long* __restrict__ packed) {
    int i = blockIdx.x * blockDim.x + threadIdx.x;
    if (i >= N_ELEMS) return;
    int b = idx[i];
    float v = vals[i];
    float vm = fdec(vmax[b]);
    float c = (float)cnt[b];
    float probs = ((v == vm) ? 1.0f : 0.0f) + 0.05f / (c - 1.0f);
    if (isinf(probs)) probs = 1.0f;   // cnt==1 -> probs=inf -> 1
    float score = logf(probs) + gumbel_val((unsigned)i);
    unsigned long long p =
        ((unsigned long long)fenc(score) << 32) | (unsigned long long)(unsigned)i;
    atomicMax(&packed[b], p);
}

// Pass 3: out row r = candidates[winner[B-1-r]], 64 floats per row.
__global__ void k_gather(const float* __restrict__ cand,
                         const unsigned long long* __restrict__ packed,
                         float* __restrict__ out) {
    int r = blockIdx.x;
    int b = BSEG - 1 - r;
    unsigned long long p = packed[b];
    unsigned id = (unsigned)(p & 0xFFFFFFFFull);
    if (p == 0ull) id = 0u;           // empty segment fallback (measure-zero)
    if (id >= N_ELEMS) id = 0u;
    out[(size_t)r * DDIM + threadIdx.x] = cand[(size_t)id * DDIM + threadIdx.x];
}

extern "C" void kernel_launch(void* const* d_in, const int* in_sizes, int n_in,
                              void* d_out, int out_size, void* d_ws, size_t ws_size,
                              hipStream_t stream) {
    const float* cand = (const float*)d_in[0];
    const float* vals = (const float*)d_in[1];
    const int*   idx  = (const int*)d_in[2];
    float* out = (float*)d_out;

    unsigned long long* packed = (unsigned long long*)d_ws;       // B * 8 bytes
    unsigned* cnt  = (unsigned*)(packed + BSEG);                  // B * 4 bytes
    unsigned* vmax = cnt + BSEG;                                  // B * 4 bytes

    hipMemsetAsync(d_ws, 0, (size_t)BSEG * 16, stream);

    k_stats <<<dim3(N_ELEMS / 256), dim3(256), 0, stream>>>(vals, idx, cnt, vmax);
    k_score <<<dim3(N_ELEMS / 256), dim3(256), 0, stream>>>(vals, idx, cnt, vmax, packed);
    k_gather<<<dim3(BSEG), dim3(DDIM), 0, stream>>>(cand, packed, out);
}

// Round 4
// 312.408 us; speedup vs baseline: 1.7606x; 1.7606x over previous
//
#include <hip/hip_runtime.h>

// GAQN actor: segmented gumbel-max sampling + reversed row gather.
// batch_idx is SORTED -> wave-level segmented scan, one atomic per run tail.

#define N_ELEMS 1048576
#define BSEG    16384
#define DDIM    64

#define GUMBEL_VARIANT 0   // 0 = JAX partitionable threefry (verified absmax=0 in R3)

__device__ __forceinline__ unsigned rotl32(unsigned x, unsigned r) {
    return (x << r) | (x >> (32u - r));
}

#define TF_ROUND(r) { x0 += x1; x1 = rotl32(x1, (r)); x1 ^= x0; }

// Threefry-2x32, 20 rounds, key = (0, 42)
__device__ __forceinline__ void tf2x32(unsigned x0, unsigned x1,
                                       unsigned& o0, unsigned& o1) {
    const unsigned k0 = 0u, k1 = 42u;
    const unsigned ks2 = k0 ^ k1 ^ 0x1BD11BDAu;
    x0 += k0; x1 += k1;
    TF_ROUND(13) TF_ROUND(15) TF_ROUND(26) TF_ROUND(6)
    x0 += k1; x1 += ks2 + 1u;
    TF_ROUND(17) TF_ROUND(29) TF_ROUND(16) TF_ROUND(24)
    x0 += ks2; x1 += k0 + 2u;
    TF_ROUND(13) TF_ROUND(15) TF_ROUND(26) TF_ROUND(6)
    x0 += k0; x1 += k1 + 3u;
    TF_ROUND(17) TF_ROUND(29) TF_ROUND(16) TF_ROUND(24)
    x0 += k1; x1 += ks2 + 4u;
    TF_ROUND(13) TF_ROUND(15) TF_ROUND(26) TF_ROUND(6)
    x0 += ks2; x1 += k0 + 5u;
    o0 = x0; o1 = x1;
}

__device__ __forceinline__ unsigned gumbel_bits(unsigned i) {
    unsigned a, b;
    tf2x32(0u, i, a, b);
    return a ^ b;          // partitionable harvest (verified bit-exact)
}

// jax.random.gumbel(key(42), (N,), f32) element i, bit-exact
__device__ __forceinline__ float gumbel_val(unsigned i) {
    unsigned bits = gumbel_bits(i);
    float f = __uint_as_float((bits >> 9) | 0x3f800000u) - 1.0f;
    const float tiny = 1.17549435e-38f;  // FLT_MIN
    float u = fmaxf(tiny, f + tiny);
    return -logf(-logf(u));
}

// Order-preserving float<->uint32 encode
__device__ __forceinline__ unsigned fenc(float f) {
    unsigned b = __float_as_uint(f);
    return (b & 0x80000000u) ? ~b : (b | 0x80000000u);
}
__device__ __forceinline__ float fdec(unsigned e) {
    unsigned b = (e & 0x80000000u) ? (e ^ 0x80000000u) : ~e;
    return __uint_as_float(b);
}

// Pass 1: per-segment count + value-max.
// Wave-segmented inclusive scan (keys sorted -> runs contiguous); only the
// tail lane of each run issues atomics.  ~32K atomics instead of 2M.
__global__ void k_stats(const float* __restrict__ vals,
                        const int* __restrict__ idx,
                        unsigned* __restrict__ cnt,
                        unsigned* __restrict__ vmax) {
    int i = blockIdx.x * 256 + threadIdx.x;
    int lane = threadIdx.x & 63;
    int b = idx[i];
    unsigned c = 1u;
    unsigned m = fenc(vals[i]);
#pragma unroll
    for (int d = 1; d < 64; d <<= 1) {
        int bo      = __shfl_up(b, d, 64);
        unsigned co = __shfl_up(c, d, 64);
        unsigned mo = __shfl_up(m, d, 64);
        if (lane >= d && bo == b) { c += co; m = (mo > m) ? mo : m; }
    }
    int bn = __shfl_down(b, 1, 64);
    if (lane == 63 || bn != b) {
        atomicAdd(&cnt[b], c);
        atomicMax(&vmax[b], m);
    }
}

// Pass 2: score = log(probs)+gumbel; wave-segmented max of packed
// (enc(score)<<32 | id); tail lane does the atomicMax.
__global__ void k_score(const float* __restrict__ vals,
                        const int* __restrict__ idx,
                        const unsigned* __restrict__ cnt,
                        const unsigned* __restrict__ vmax,
                        unsigned long long* __restrict__ packed) {
    int i = blockIdx.x * 256 + threadIdx.x;
    int lane = threadIdx.x & 63;
    int b = idx[i];
    float v = vals[i];
    float vm = fdec(vmax[b]);          // broadcast L2 hit (same b across wave)
    float c = (float)cnt[b];
    float probs = ((v == vm) ? 1.0f : 0.0f) + 0.05f / (c - 1.0f);
    if (isinf(probs)) probs = 1.0f;    // cnt==1 -> inf -> 1
    float score = logf(probs) + gumbel_val((unsigned)i);
    unsigned long long p =
        ((unsigned long long)fenc(score) << 32) | (unsigned long long)(unsigned)i;
#pragma unroll
    for (int d = 1; d < 64; d <<= 1) {
        int bo = __shfl_up(b, d, 64);
        unsigned long long po = __shfl_up(p, d, 64);
        if (lane >= d && bo == b) { p = (po > p) ? po : p; }
    }
    int bn = __shfl_down(b, 1, 64);
    if (lane == 63 || bn != b) atomicMax(&packed[b], p);
}

// Pass 3: out row r = candidates[winner[B-1-r]], float4 x 16 lanes per row.
__global__ void k_gather(const float4* __restrict__ cand,
                         const unsigned long long* __restrict__ packed,
                         float4* __restrict__ out) {
    int t = blockIdx.x * 256 + threadIdx.x;
    int r = t >> 4;                    // output row
    int q = t & 15;                    // float4 index within row (64 f32 = 16 f4)
    unsigned long long p = packed[BSEG - 1 - r];
    unsigned id = (unsigned)(p & 0xFFFFFFFFull);
    if (p == 0ull || id >= N_ELEMS) id = 0u;   // empty-segment fallback
    out[(size_t)r * 16 + q] = cand[(size_t)id * 16 + q];
}

extern "C" void kernel_launch(void* const* d_in, const int* in_sizes, int n_in,
                              void* d_out, int out_size, void* d_ws, size_t ws_size,
                              hipStream_t stream) {
    const float* cand = (const float*)d_in[0];
    const float* vals = (const float*)d_in[1];
    const int*   idx  = (const int*)d_in[2];
    float* out = (float*)d_out;

    unsigned long long* packed = (unsigned long long*)d_ws;       // B * 8 B
    unsigned* cnt  = (unsigned*)(packed + BSEG);                  // B * 4 B
    unsigned* vmax = cnt + BSEG;                                  // B * 4 B

    hipMemsetAsync(d_ws, 0, (size_t)BSEG * 16, stream);

    k_stats <<<dim3(N_ELEMS / 256), dim3(256), 0, stream>>>(vals, idx, cnt, vmax);
    k_score <<<dim3(N_ELEMS / 256), dim3(256), 0, stream>>>(vals, idx, cnt, vmax, packed);
    k_gather<<<dim3(BSEG * 16 / 256), dim3(256), 0, stream>>>(
        (const float4*)cand, packed, (float4*)out);
}